// Round 12
// baseline (151.323 us; speedup 1.0000x reference)
//
#include <hip/hip_runtime.h>
#include <hip/hip_bf16.h>

// ---------------------------------------------------------------------------
// DropBlock fused dual-conv as implicit GEMM. Tile 224x128, 256 threads
// (4 waves of 112x64), TWO blocks co-resident per CU (m114/m97 overlap:
// independent blocks cover each other's barrier/waitcnt stalls).
//   M = 50176 (224 M-tiles), N = 512 (4 quarters of 128), K = 2304.
//   72 K-tiles of 32; 2-slot LDS double-buffer (22528 B/slot), depth-1,
//   VM(0)+BAR per tile (uniform drain -> masked staging op is safe).
// Per tile: stage t+1 (6 gll16: 4xA [4th masked tid<128] + 2xB) ->
//   ds av0(4)+bv(4) -> ds av1(3) -> LGKM(3) -> MFMA mh0 (16) ->
//   LGKM(0) -> MFMA mh1 (12) -> VM(0) -> BAR.
// Slot WAR: stage into slot (t+1)&1 = t-1's slot; t-1's ds reads drained at
//   its LGKM(0) before its end-BAR. LDS padded to 55296 B to cap 2 blocks/CU.
// ws: [0,4) dropped | [1024,+50176) sel | [65536,+29491200) xt bf16
//     [64][30][30][256] | [+2359296) wt bf16 [72 t][4 nq][128 rows][4 ps][8]
// ---------------------------------------------------------------------------

typedef __bf16  bf16x8 __attribute__((ext_vector_type(8)));
typedef float   f32x4  __attribute__((ext_vector_type(4)));
typedef unsigned int u32;
typedef unsigned short u16;

#define XT_OFF     65536
#define WT_OFF     (65536 + 29491200)
#define SEL_OFF    1024
#define SLOT       22528

__device__ __forceinline__ u16 f2bf(float v) {
    u32 u = __float_as_uint(v);
    u32 r = (u + 0x7FFFu + ((u >> 16) & 1u)) >> 16;
    return (u16)r;
}

__device__ __forceinline__ void gll16(const void* g, void* l) {
    __builtin_amdgcn_global_load_lds(
        (const __attribute__((address_space(1))) u32*)g,
        (__attribute__((address_space(3))) u32*)l, 16, 0, 0);
}

// ---------------- fused prep: xt transform + wt swizzle + mask -------------
__global__ void prep_kernel(const float* __restrict__ x,
                            const float* __restrict__ wl,
                            const float* __restrict__ wp,
                            const float* __restrict__ mu,
                            u16* __restrict__ xt, u16* __restrict__ wt,
                            unsigned char* __restrict__ sel,
                            int* __restrict__ dropped) {
    int b = blockIdx.x, tid = threadIdx.x;
    if (b < 1920) {                                   // ---- xt: 64*30 rows
        int n = b / 30, oh = b % 30;
        u16* row = xt + (size_t)(n * 30 + oh) * 30 * 256;
        if (oh == 0 || oh == 29) {                    // halo rows: full zero
            u32* r32 = (u32*)row;
            #pragma unroll
            for (int i = 0; i < 15; ++i) r32[i * 256 + tid] = 0;
            return;
        }
        int h = oh - 1;
        row[tid] = 0;
        row[29 * 256 + tid] = 0;
        const float* src = x + ((size_t)(n * 256 + tid) * 28 + h) * 28;
        float f[28];
        #pragma unroll
        for (int q = 0; q < 7; ++q) {
            float4 v = *(const float4*)(src + q * 4);
            f[q * 4 + 0] = v.x; f[q * 4 + 1] = v.y;
            f[q * 4 + 2] = v.z; f[q * 4 + 3] = v.w;
        }
        #pragma unroll
        for (int w = 0; w < 28; ++w)
            row[(1 + w) * 256 + tid] = f2bf(f[w]);
    } else if (b < 6528) {                            // ---- wt blocks
        // block bb = t*4 + nq: [row 0..127][ps 0..3][jj 0..7]
        // phys slot ps holds logical channels (ps ^ ((row>>1)&3))*8 + jj
        int gid = (b - 1920) * 256 + tid;             // 1179648 exact
        int bb = gid >> 12;                           // 0..287
        int e = gid & 4095;
        int t = bb >> 2, nq = bb & 3;
        int kk = t >> 3;                              // tap 0..8
        int row = e >> 5, r2 = e & 31;
        int ps = r2 >> 3, jj = r2 & 7;
        int c = (t & 7) * 32 + ((ps ^ ((row >> 1) & 3)) << 3) + jj;
        int o = nq * 128 + row;
        const float* wsrc = (o < 256) ? wl : wp;
        wt[gid] = f2bf(wsrc[((size_t)(o & 255) * 256 + c) * 9 + kk]);
    } else {                                          // ---- mask + pooled sel
        int m = (b - 6528) * 256 + tid;               // 196*256 exact
        int n = m / 784, rem = m % 784;
        int h = rem / 28, w = rem % 28;
        const float g = (float)(0.1 / 49.0);
        const float* un = mu + n * 784;
        int p = 0;
        for (int dy = -3; dy <= 3; ++dy) {
            int hh = h + dy;
            if (hh < 0 || hh >= 28) continue;
            for (int dx = -3; dx <= 3; ++dx) {
                int ww = w + dx;
                if (ww < 0 || ww >= 28) continue;
                p |= (un[hh * 28 + ww] < g) ? 1 : 0;
            }
        }
        sel[m] = (unsigned char)p;
        unsigned long long bl = __ballot(p);
        if ((tid & 63) == 0) atomicAdd(dropped, __popcll(bl));
    }
}

// ---------------- implicit-GEMM conv + select + scale ----------------------
__global__ __launch_bounds__(256, 2)
void conv_kernel(const char* __restrict__ xt,    // bf16 padded NHWC (bytes)
                 const char* __restrict__ wt,    // bf16 swizzled blocks (bytes)
                 const unsigned char* __restrict__ sel,
                 const int* __restrict__ dropped,
                 float* __restrict__ out) {
    __shared__ char smem[55296];                  // 2 slots x 22528 (+pad)
    const int tid = threadIdx.x;
    const int lb = (blockIdx.x & 7) * 112 + (blockIdx.x >> 3);  // 896 = 8*112
    const int bm = lb >> 2;                  // 224 M-tiles of 224 positions
    const int bnq = lb & 3;                  // N-quarter: 0,1 -> a ; 2,3 -> b
    const int lane = tid & 63, wave = tid >> 6;
    const int lane15 = lane & 15, grp = lane >> 4;
    const int wm = wave >> 1, wn = wave & 1; // per-wave 112 x 64 output

    // --- A staging source bases; source-side swizzle folded in ---
    // op i (i<3): rows i*64 + (tid>>2); op 3 (tid<128): rows 192 + (tid>>2)
    long pbA[4];
    {
        int swz = ((tid & 3) ^ ((tid >> 3) & 3)) << 4;
        #pragma unroll
        for (int i = 0; i < 4; ++i) {
            int r = i * 64 + (tid >> 2);
            int m = bm * 224 + r;
            if (m > 50175) m = 50175;        // masked-op lanes: unused addr
            int n = m / 784, rem = m % 784;
            pbA[i] = (long)(((n * 30 + rem / 28 + 1) * 30 + (rem % 28 + 1)) * 512
                            + swz);
        }
    }

    f32x4 acc[7][4];
    #pragma unroll
    for (int i = 0; i < 7; ++i)
        #pragma unroll
        for (int j = 0; j < 4; ++j)
            acc[i][j] = (f32x4){0.f, 0.f, 0.f, 0.f};

    const int so  = (grp ^ ((lane15 >> 1) & 3)) << 4;        // read swizzle
    const int arb = wm * 7168 + (lane15 << 6) + so;          // A base in slot
    const int brb = 14336 + wn * 4096 + (lane15 << 6) + so;  // B base in slot

#define AON(TC) ((long)((TC) >> 3) / 3 * 15360 + (long)(((TC) >> 3) % 3) * 512 \
                 - 15872 + (long)(((TC) & 7) << 6))
#define STG(TC, SL) { char* sd_ = smem + (SL) * SLOT;                       \
        const long ao_ = AON(TC);                                           \
        gll16(xt + pbA[0] + ao_, sd_ + (tid << 4));                         \
        gll16(xt + pbA[1] + ao_, sd_ + 4096 + (tid << 4));                  \
        gll16(xt + pbA[2] + ao_, sd_ + 8192 + (tid << 4));                  \
        if (tid < 128) gll16(xt + pbA[3] + ao_, sd_ + 12288 + (tid << 4));  \
        const char* wb_ = wt + ((size_t)((TC) * 4 + bnq) << 13);            \
        gll16(wb_ + (tid << 4), sd_ + 14336 + (tid << 4));                  \
        gll16(wb_ + 4096 + (tid << 4), sd_ + 18432 + (tid << 4)); }
#define DS_AV0(dst, SL) { const char* sb_ = smem + (SL) * SLOT;             \
        _Pragma("unroll")                                                   \
        for (int fm = 0; fm < 4; ++fm)                                      \
            dst[fm] = *(const bf16x8*)(sb_ + arb + (fm << 10)); }
#define DS_AV1(dst, SL) { const char* sb_ = smem + (SL) * SLOT + 4096;      \
        _Pragma("unroll")                                                   \
        for (int fm = 0; fm < 3; ++fm)                                      \
            dst[fm] = *(const bf16x8*)(sb_ + arb + (fm << 10)); }
#define DS_BV(dst, SL) { const char* sb_ = smem + (SL) * SLOT;              \
        _Pragma("unroll")                                                   \
        for (int fn = 0; fn < 4; ++fn)                                      \
            dst[fn] = *(const bf16x8*)(sb_ + brb + (fn << 10)); }
#define MM(A0_, NF, AV, BV) { __builtin_amdgcn_s_setprio(1);                \
        _Pragma("unroll")                                                   \
        for (int fm = 0; fm < (NF); ++fm)                                   \
            _Pragma("unroll")                                               \
            for (int fn = 0; fn < 4; ++fn)                                  \
                acc[(A0_)+fm][fn] = __builtin_amdgcn_mfma_f32_16x16x32_bf16( \
                    AV[fm], BV[fn], acc[(A0_)+fm][fn], 0, 0, 0);            \
        __builtin_amdgcn_s_setprio(0); }
#define LGKM(N) { asm volatile("s_waitcnt lgkmcnt(" #N ")" ::: "memory");   \
                  __builtin_amdgcn_sched_barrier(0); }
#define VM0     { asm volatile("s_waitcnt vmcnt(0)" ::: "memory");          \
                  __builtin_amdgcn_sched_barrier(0); }
#define BAR     asm volatile("s_barrier" ::: "memory")

    bf16x8 av0[4], av1[3], bv[4];

    // --- prologue: stage tile 0 into slot 0 ---
    STG(0, 0);
    VM0;
    BAR;

    for (int t = 0; t < 72; ++t) {
        const int sc = t & 1, ss = sc ^ 1;
        if (t < 71) STG(t + 1, ss);
        DS_AV0(av0, sc);
        DS_BV(bv, sc);
        DS_AV1(av1, sc);
        LGKM(3);                    // av0+bv ready; av1 still landing
        MM(0, 4, av0, bv);
        LGKM(0);                    // av1 ready
        MM(4, 3, av1, bv);
        VM0;                        // tile t+1 staged & landed
        BAR;
    }

    // --- epilogue: per-wave LDS transpose -> coalesced predicated stores ---
    float scale = 50176.0f / (float)(50176 - *dropped);
    float* ep = (float*)smem + wave * 2080;      // private [32][65] f32
    __syncthreads();
    #pragma unroll
    for (int rr = 0; rr < 4; ++rr) {
        const int r2 = rr & 1;        // 32-channel half of this wave's 64
        const int mh = rr >> 1;       // m half: 0 -> 64 pos, 1 -> 48 pos
        const int nf = mh ? 3 : 4;
        for (int fm2 = 0; fm2 < nf; ++fm2)
            #pragma unroll
            for (int f2 = 0; f2 < 2; ++f2)
                #pragma unroll
                for (int j = 0; j < 4; ++j)
                    ep[(f2 * 16 + lane15) * 65 + fm2 * 16 + grp * 4 + j] =
                        acc[mh * 4 + fm2][r2 * 2 + f2][j];
        __syncthreads();
        if (mh == 0 || lane < 48) {
            int p = bm * 224 + wm * 112 + mh * 64 + lane;
            int n = p / 784, rem = p % 784;
            unsigned char sv = sel[p];
            bool want = (bnq >= 2) ? (sv != 0) : (sv == 0);
            size_t ob = (size_t)n * 200704 + rem;
            if (want) {
                #pragma unroll
                for (int ch = 0; ch < 32; ++ch) {
                    int c = (bnq * 128 + wn * 64 + r2 * 32 + ch) & 255;
                    out[ob + (size_t)c * 784] = ep[ch * 65 + lane] * scale;
                }
            }
        }
        __syncthreads();
    }
#undef AON
#undef STG
#undef DS_AV0
#undef DS_AV1
#undef DS_BV
#undef MM
#undef LGKM
#undef VM0
#undef BAR
}

// ---------------------------------------------------------------------------
extern "C" void kernel_launch(void* const* d_in, const int* in_sizes, int n_in,
                              void* d_out, int out_size, void* d_ws, size_t ws_size,
                              hipStream_t stream) {
    const float* x  = (const float*)d_in[0];
    const float* wl = (const float*)d_in[1];
    const float* wp = (const float*)d_in[2];
    const float* mu = (const float*)d_in[3];
    float* out = (float*)d_out;
    char* ws = (char*)d_ws;

    int* dropped = (int*)ws;
    unsigned char* sel = (unsigned char*)(ws + SEL_OFF);
    u16* xt = (u16*)(ws + XT_OFF);
    u16* wt = (u16*)(ws + WT_OFF);

    hipMemsetAsync(ws, 0, 4, stream);

    prep_kernel<<<6724, 256, 0, stream>>>(x, wl, wp, mu, xt, wt, sel, dropped);
    conv_kernel<<<896, 256, 0, stream>>>((const char*)xt, (const char*)wt,
                                         sel, dropped, out);
}